// Round 2
// 477.307 us; speedup vs baseline: 1.1409x; 1.1409x over previous
//
#include <hip/hip_runtime.h>
#include <cstdio>

#define NN 50000
#define NE 800000
#define DD 256
#define WS_NEED 113080000UL

__attribute__((constructor)) static void r14_on_load(void) {
    fprintf(stderr, "R14SO_LOADED\n");
    fflush(stderr);
}

__device__ float b2f(unsigned short u) {
    union { unsigned int i; float f; } c;
    c.i = ((unsigned int)u) << 16;
    return c.f;
}
__device__ float clampf(float v) { return fminf(fmaxf(v, -65504.f), 65504.f); }
__device__ float rdF(const void* p, long long idx, int ff) {
    if (ff) return clampf(b2f(((const unsigned short*)p)[idx]));
    return clampf(((const float*)p)[idx]);
}
__device__ unsigned short f2b_rne(float f) {
    union { float f; unsigned int u; } c;
    c.f = f;
    unsigned int r = (c.u + 0x7FFFu + ((c.u >> 16) & 1u)) >> 16;
    return (unsigned short)r;
}

typedef __attribute__((ext_vector_type(8))) short bf16x8;
typedef __attribute__((ext_vector_type(4))) float f32x4;

__global__ void g_zero(int* deg, float* sums) {
    int i = blockIdx.x * 256 + threadIdx.x;
    if (i < NN) deg[i] = 0;
    if (i < 2 * DD) sums[i] = 0.f;
}

/* dtype detection (fp32 vs bf16 x; int64 vs int32 edges).
   rocprof round-12 evidence: g_gemm FETCH ~26MB => x IS bf16 on the harness. */
__global__ void g_detect(const unsigned short* xr, const int* ei, int* flags) {
    __shared__ int acc[2];
    if (threadIdx.x < 2) acc[threadIdx.x] = 0;
    __syncthreads();
    int g = 0;
    for (int j = 0; j < 4; j++) {
        unsigned short u = xr[(threadIdx.x * 4 + j) * 2];
        int e = (u >> 7) & 0xFF;
        if (u == 0 || u == 0x8000 || (e >= 100 && e <= 140)) g++;
    }
    atomicAdd(&acc[0], g);
    if (ei[2 * threadIdx.x + 1] != 0) atomicAdd(&acc[1], 1);
    __syncthreads();
    if (threadIdx.x == 0) {
        flags[0] = (acc[0] >= 922) ? 1 : 0; /* 1 => bf16 floats */
        flags[1] = (acc[1] == 0) ? 1 : 0;   /* 1 => int64 edges */
    }
}

__global__ void g_cvt_e(const int* raw, const int* flags, int* e32) {
    int i = blockIdx.x * 256 + threadIdx.x;
    if (i < 2 * NE) e32[i] = flags[1] ? raw[2 * i] : raw[i];
}

/* W -> bf16, SAME layout as input W: [o][k] row-major.
   B-fragment lanes then read 8 contiguous k => single dwordx4. */
__global__ void g_cvt_w(const void* W, const int* flags, unsigned short* Wb) {
    int i = blockIdx.x * 256 + threadIdx.x;
    Wb[i] = f2b_rne(rdF(W, i, flags[0]));
}

__global__ void g_cvt_p(const void* bias, const void* gamma, const void* beta,
                        const int* flags, float* pf) {
    int t = threadIdx.x;
    int ff = flags[0];
    pf[t] = rdF(bias, t, ff);
    pf[DD + t] = rdF(gamma, t, ff);
    pf[2 * DD + t] = rdF(beta, t, ff);
}

/* MFMA GEMM: h[n][o] = sum_k x[n][k] * W[o][k], fp32 accumulate.
   One wave per 16 rows. 3125 row-tiles; grid 782 blocks x 4 waves.
   A frag: lane holds x[r0 + (lane&15)][kstep*32 + (lane>>4)*8 + j], j=0..7
   B frag: lane holds W[ct*16 + (lane&15)][kstep*32 + (lane>>4)*8 + j]
   C/D:    col = lane&15, row = (lane>>4)*4 + reg   (m89-verified mapping) */
__global__ __launch_bounds__(256) void g_gemm_mfma(const void* x, const int* flags,
                                                   const unsigned short* Wb, float* h) {
    int wave = threadIdx.x >> 6;
    int lane = threadIdx.x & 63;
    int gw = blockIdx.x * 4 + wave;
    if (gw >= 3125) return;
    int r0 = gw * 16;
    int l15 = lane & 15;
    int kq = lane >> 4;

    bf16x8 a[8];
    int ff = flags[0];
    if (ff) {
        const unsigned short* p =
            (const unsigned short*)x + (unsigned long long)(r0 + l15) * DD + kq * 8;
#pragma unroll
        for (int k = 0; k < 8; k++)
            a[k] = *(const bf16x8*)(p + k * 32);
    } else {
        const float* p = (const float*)x + (unsigned long long)(r0 + l15) * DD + kq * 8;
#pragma unroll
        for (int k = 0; k < 8; k++) {
#pragma unroll
            for (int j = 0; j < 8; j++)
                a[k][j] = (short)f2b_rne(p[k * 32 + j]);
        }
    }

#pragma unroll
    for (int ct = 0; ct < 16; ct++) {
        const unsigned short* q = Wb + (unsigned long long)(ct * 16 + l15) * DD + kq * 8;
        f32x4 acc = {0.f, 0.f, 0.f, 0.f};
#pragma unroll
        for (int k = 0; k < 8; k++) {
            bf16x8 b = *(const bf16x8*)(q + k * 32);
            acc = __builtin_amdgcn_mfma_f32_16x16x32_bf16(a[k], b, acc, 0, 0, 0);
        }
        float* op = h + (unsigned long long)(r0 + kq * 4) * DD + ct * 16 + l15;
#pragma unroll
        for (int j = 0; j < 4; j++)
            op[(unsigned long long)j * DD] = acc[j];
    }
}

__global__ void g_degree(const int* erow, const int* ecol, int* deg) {
    int e = blockIdx.x * 256 + threadIdx.x;
    if (e < NE) {
        unsigned int c = (unsigned int)ecol[e];
        unsigned int r = (unsigned int)erow[e];
        if (c < NN && r < NN) atomicAdd(&deg[c], 1);
    }
}

__global__ void g_dinv(const int* deg, float* dinv) {
    int n = blockIdx.x * 256 + threadIdx.x;
    if (n < NN) dinv[n] = rsqrtf((float)(deg[n] + 1));
}

__global__ __launch_bounds__(256) void g_scan1(const int* deg, int* off, int* bsum) {
    __shared__ int sm[256];
    int tid = threadIdx.x;
    int i = blockIdx.x * 256 + tid;
    int v = (i < NN) ? deg[i] : 0;
    sm[tid] = v;
    __syncthreads();
    for (int s = 1; s < 256; s <<= 1) {
        int t = (tid >= s) ? sm[tid - s] : 0;
        __syncthreads();
        sm[tid] += t;
        __syncthreads();
    }
    if (i < NN) off[i] = sm[tid] - v;
    if (tid == 255) bsum[blockIdx.x] = sm[255];
}

__global__ __launch_bounds__(256) void g_scan2(const int* bsum, int* bbase) {
    __shared__ int sm[256];
    int tid = threadIdx.x;
    int v = (tid < 196) ? bsum[tid] : 0;
    sm[tid] = v;
    __syncthreads();
    for (int s = 1; s < 256; s <<= 1) {
        int t = (tid >= s) ? sm[tid - s] : 0;
        __syncthreads();
        sm[tid] += t;
        __syncthreads();
    }
    if (tid < 196) bbase[tid] = sm[tid] - v;
}

__global__ void g_scan3(int* off, const int* bbase, int* cursor) {
    int i = blockIdx.x * 256 + threadIdx.x;
    if (i < NN) {
        int o = off[i] + bbase[i >> 8];
        off[i] = o;
        cursor[i] = o;
    }
}

__global__ void g_fill(const int* erow, const int* ecol, int* cursor, int* csrc) {
    int e = blockIdx.x * 256 + threadIdx.x;
    if (e < NE) {
        unsigned int c = (unsigned int)ecol[e];
        unsigned int r = (unsigned int)erow[e];
        if (c < NN && r < NN) {
            int slot = atomicAdd(&cursor[c], 1);
            if ((unsigned int)slot < NE) csrc[slot] = (int)r;
        }
    }
}

/* aggregate + bias -> fp32 agg. one wave per node, lane owns 4 features */
__global__ __launch_bounds__(256) void g_agg(const float* h, const float* dinv,
                                             const int* off, const int* deg,
                                             const int* csrc, const float* pf,
                                             float* agg) {
    int lane = threadIdx.x & 63;
    int n = blockIdx.x * 4 + (threadIdx.x >> 6);
    int f0 = lane * 4;
    float dn = dinv[n];
    float ws = dn * dn;
    const float* hp = h + (unsigned long long)n * DD + f0;
    float a0 = hp[0] * ws;
    float a1 = hp[1] * ws;
    float a2 = hp[2] * ws;
    float a3 = hp[3] * ws;
    int s = off[n];
    int cnt = deg[n];
    for (int i = 0; i < cnt; i++) {
        int src = csrc[s + i];
        if ((unsigned int)src >= NN) continue;
        float wgt = dinv[src] * dn;
        const float* hq = h + (unsigned long long)src * DD + f0;
        a0 += hq[0] * wgt;
        a1 += hq[1] * wgt;
        a2 += hq[2] * wgt;
        a3 += hq[3] * wgt;
    }
    float* op = agg + (unsigned long long)n * DD + f0;
    op[0] = a0 + pf[f0 + 0];
    op[1] = a1 + pf[f0 + 1];
    op[2] = a2 + pf[f0 + 2];
    op[3] = a3 + pf[f0 + 3];
}

__global__ __launch_bounds__(256) void g_stats(const float* agg, float* sums) {
    int t = threadIdx.x;
    float s = 0.f;
    float s2 = 0.f;
    for (int n = blockIdx.x; n < NN; n += 256) {
        float v = agg[(unsigned long long)n * DD + t];
        s += v;
        s2 += v * v;
    }
    atomicAdd(&sums[t], s);
    atomicAdd(&sums[DD + t], s2);
}

__global__ void g_fin(const float* sums, const float* pf, float* ss) {
    int t = threadIdx.x;
    float mean = sums[t] * (1.0f / NN);
    float var = sums[DD + t] * (1.0f / NN) - mean * mean;
    var = fmaxf(var, 0.f);
    float sc = pf[DD + t] * rsqrtf(var + 1e-5f);
    ss[t] = sc;
    ss[DD + t] = pf[2 * DD + t] - mean * sc;
}

/* BN + ReLU: fp32 agg -> FP32 out */
__global__ void DenseGCNLayer_2937757631000_kernel(const float* agg, const float* ss,
                                                   float* out) {
    int t = threadIdx.x;
    unsigned long long i = (unsigned long long)blockIdx.x * DD + t;
    float v = agg[i];
    out[i] = fmaxf(ss[t] * v + ss[DD + t], 0.f);
}

extern "C" void kernel_launch(void* const* d_in, const int* in_sizes, int n_in,
                              void* d_out, int out_size, void* d_ws, size_t ws_size,
                              hipStream_t stream) {
    const void* x = d_in[0];
    const int* ei = (const int*)d_in[1];
    const void* W = d_in[2];
    const void* bias = d_in[3];
    const void* gamma = d_in[4];
    const void* beta = d_in[5];
    char* ws = (char*)d_ws;
    float* out = (float*)d_out;

    float* h = (float*)(ws + 0UL);            /* 51.2 MB fp32 */
    float* agg = (float*)(ws + 51200000UL);   /* 51.2 MB fp32 */
    int* e32 = (int*)(ws + 102400000UL);      /* 6.4 MB */
    int* csrc = (int*)(ws + 108800000UL);     /* 3.2 MB */
    unsigned short* Wb = (unsigned short*)(ws + 112000000UL); /* 128 KB bf16 */
    int* deg = (int*)(ws + 112262144UL);
    float* dinv = (float*)(ws + 112462336UL);
    int* off = (int*)(ws + 112662528UL);
    int* cursor = (int*)(ws + 112862720UL);
    int* bsum = (int*)(ws + 113062912UL);
    int* bbase = (int*)(ws + 113063936UL);
    float* pf = (float*)(ws + 113064960UL);
    float* sums = (float*)(ws + 113068032UL);
    float* ss = (float*)(ws + 113070080UL);
    int* flags = (int*)(ws + 113072128UL);
    const int* erow = e32;
    const int* ecol = e32 + NE;

    if (ws_size < WS_NEED) {
        fprintf(stderr, "R14_WS_SMALL %zu\n", ws_size);
        fflush(stderr);
        return;
    }

    g_zero<<<196, 256, 0, stream>>>(deg, sums);
    g_detect<<<1, 256, 0, stream>>>((const unsigned short*)x, ei, flags);
    g_cvt_e<<<6250, 256, 0, stream>>>(ei, flags, e32);
    g_cvt_w<<<DD, 256, 0, stream>>>(W, flags, Wb);
    g_cvt_p<<<1, 256, 0, stream>>>(bias, gamma, beta, flags, pf);
    g_gemm_mfma<<<782, 256, 0, stream>>>(x, flags, Wb, h);
    g_degree<<<3125, 256, 0, stream>>>(erow, ecol, deg);
    g_dinv<<<196, 256, 0, stream>>>(deg, dinv);
    g_scan1<<<196, 256, 0, stream>>>(deg, off, bsum);
    g_scan2<<<1, 256, 0, stream>>>(bsum, bbase);
    g_scan3<<<196, 256, 0, stream>>>(off, bbase, cursor);
    g_fill<<<3125, 256, 0, stream>>>(erow, ecol, cursor, csrc);
    g_agg<<<12500, 256, 0, stream>>>(h, dinv, off, deg, csrc, pf, agg);
    g_stats<<<256, 256, 0, stream>>>(agg, sums);
    g_fin<<<1, 256, 0, stream>>>(sums, pf, ss);
    DenseGCNLayer_2937757631000_kernel<<<50000, 256, 0, stream>>>(agg, ss, out);
}

// Round 3
// 423.872 us; speedup vs baseline: 1.2847x; 1.1261x over previous
//
#include <hip/hip_runtime.h>
#include <cstdio>

#define NN 50000
#define NE 800000
#define DD 256
#define WS_NEED 113080000UL

__attribute__((constructor)) static void r15_on_load(void) {
    fprintf(stderr, "R15SO_LOADED\n");
    fflush(stderr);
}

__device__ float b2f(unsigned short u) {
    union { unsigned int i; float f; } c;
    c.i = ((unsigned int)u) << 16;
    return c.f;
}
__device__ float clampf(float v) { return fminf(fmaxf(v, -65504.f), 65504.f); }
__device__ float rdF(const void* p, long long idx, int ff) {
    if (ff) return clampf(b2f(((const unsigned short*)p)[idx]));
    return clampf(((const float*)p)[idx]);
}
__device__ unsigned short f2b_rne(float f) {
    union { float f; unsigned int u; } c;
    c.f = f;
    unsigned int r = (c.u + 0x7FFFu + ((c.u >> 16) & 1u)) >> 16;
    return (unsigned short)r;
}

typedef __attribute__((ext_vector_type(8))) short bf16x8;
typedef __attribute__((ext_vector_type(4))) float f32x4;
typedef __attribute__((ext_vector_type(4))) _Float16 f16x4;

__global__ void g_zero(int* deg, float* sums) {
    int i = blockIdx.x * 256 + threadIdx.x;
    if (i < NN) deg[i] = 0;
    if (i < 2 * DD) sums[i] = 0.f;
}

/* dtype detection (fp32 vs bf16 x; int64 vs int32 edges). */
__global__ void g_detect(const unsigned short* xr, const int* ei, int* flags) {
    __shared__ int acc[2];
    if (threadIdx.x < 2) acc[threadIdx.x] = 0;
    __syncthreads();
    int g = 0;
    for (int j = 0; j < 4; j++) {
        unsigned short u = xr[(threadIdx.x * 4 + j) * 2];
        int e = (u >> 7) & 0xFF;
        if (u == 0 || u == 0x8000 || (e >= 100 && e <= 140)) g++;
    }
    atomicAdd(&acc[0], g);
    if (ei[2 * threadIdx.x + 1] != 0) atomicAdd(&acc[1], 1);
    __syncthreads();
    if (threadIdx.x == 0) {
        flags[0] = (acc[0] >= 922) ? 1 : 0; /* 1 => bf16 floats */
        flags[1] = (acc[1] == 0) ? 1 : 0;   /* 1 => int64 edges */
    }
}

/* fused edge convert + degree count (one pass over raw edges) */
__global__ void g_cvt_ed(const int* raw, const int* flags, int* e32, int* deg) {
    int e = blockIdx.x * 256 + threadIdx.x;
    if (e >= NE) return;
    int f = flags[1];
    int r = f ? raw[2 * e] : raw[e];
    int c = f ? raw[2 * (NE + e)] : raw[NE + e];
    e32[e] = r;
    e32[NE + e] = c;
    if ((unsigned int)r < NN && (unsigned int)c < NN) atomicAdd(&deg[c], 1);
}

/* W -> bf16, SAME layout as input W: [o][k] row-major. */
__global__ void g_cvt_w(const void* W, const int* flags, unsigned short* Wb) {
    int i = blockIdx.x * 256 + threadIdx.x;
    Wb[i] = f2b_rne(rdF(W, i, flags[0]));
}

__global__ void g_cvt_p(const void* bias, const void* gamma, const void* beta,
                        const int* flags, float* pf) {
    int t = threadIdx.x;
    int ff = flags[0];
    pf[t] = rdF(bias, t, ff);
    pf[DD + t] = rdF(gamma, t, ff);
    pf[2 * DD + t] = rdF(beta, t, ff);
}

/* MFMA GEMM: h[n][o] = sum_k x[n][k] * W[o][k], fp32 accumulate, fp16 store.
   A frag: lane holds x[r0 + (lane&15)][(lane>>4)*8 + j + 32k]
   B frag: lane holds W[ct*16 + (lane&15)][(lane>>4)*8 + j + 32k]
   C/D:    col = lane&15, row = (lane>>4)*4 + reg   (m89-verified mapping) */
__global__ __launch_bounds__(256) void g_gemm_mfma(const void* x, const int* flags,
                                                   const unsigned short* Wb,
                                                   _Float16* h) {
    int wave = threadIdx.x >> 6;
    int lane = threadIdx.x & 63;
    int gw = blockIdx.x * 4 + wave;
    if (gw >= 3125) return;
    int r0 = gw * 16;
    int l15 = lane & 15;
    int kq = lane >> 4;

    bf16x8 a[8];
    int ff = flags[0];
    if (ff) {
        const unsigned short* p =
            (const unsigned short*)x + (unsigned long long)(r0 + l15) * DD + kq * 8;
#pragma unroll
        for (int k = 0; k < 8; k++)
            a[k] = *(const bf16x8*)(p + k * 32);
    } else {
        const float* p = (const float*)x + (unsigned long long)(r0 + l15) * DD + kq * 8;
#pragma unroll
        for (int k = 0; k < 8; k++) {
#pragma unroll
            for (int j = 0; j < 8; j++)
                a[k][j] = (short)f2b_rne(p[k * 32 + j]);
        }
    }

#pragma unroll
    for (int ct = 0; ct < 16; ct++) {
        const unsigned short* q = Wb + (unsigned long long)(ct * 16 + l15) * DD + kq * 8;
        f32x4 acc = {0.f, 0.f, 0.f, 0.f};
#pragma unroll
        for (int k = 0; k < 8; k++) {
            bf16x8 b = *(const bf16x8*)(q + k * 32);
            acc = __builtin_amdgcn_mfma_f32_16x16x32_bf16(a[k], b, acc, 0, 0, 0);
        }
        _Float16* op = h + (unsigned long long)(r0 + kq * 4) * DD + ct * 16 + l15;
#pragma unroll
        for (int j = 0; j < 4; j++)
            op[(unsigned long long)j * DD] = (_Float16)acc[j];
    }
}

/* scan1 also emits dinv (has deg[i] in-register already) */
__global__ __launch_bounds__(256) void g_scan1(const int* deg, int* off, int* bsum,
                                               float* dinv) {
    __shared__ int sm[256];
    int tid = threadIdx.x;
    int i = blockIdx.x * 256 + tid;
    int v = (i < NN) ? deg[i] : 0;
    sm[tid] = v;
    __syncthreads();
    for (int s = 1; s < 256; s <<= 1) {
        int t = (tid >= s) ? sm[tid - s] : 0;
        __syncthreads();
        sm[tid] += t;
        __syncthreads();
    }
    if (i < NN) {
        off[i] = sm[tid] - v;
        dinv[i] = rsqrtf((float)(v + 1));
    }
    if (tid == 255) bsum[blockIdx.x] = sm[255];
}

__global__ __launch_bounds__(256) void g_scan2(const int* bsum, int* bbase) {
    __shared__ int sm[256];
    int tid = threadIdx.x;
    int v = (tid < 196) ? bsum[tid] : 0;
    sm[tid] = v;
    __syncthreads();
    for (int s = 1; s < 256; s <<= 1) {
        int t = (tid >= s) ? sm[tid - s] : 0;
        __syncthreads();
        sm[tid] += t;
        __syncthreads();
    }
    if (tid < 196) bbase[tid] = sm[tid] - v;
}

__global__ void g_scan3(int* off, const int* bbase, int* cursor) {
    int i = blockIdx.x * 256 + threadIdx.x;
    if (i < NN) {
        int o = off[i] + bbase[i >> 8];
        off[i] = o;
        cursor[i] = o;
    }
}

__global__ void g_fill(const int* erow, const int* ecol, int* cursor, int* csrc) {
    int e = blockIdx.x * 256 + threadIdx.x;
    if (e < NE) {
        unsigned int c = (unsigned int)ecol[e];
        unsigned int r = (unsigned int)erow[e];
        if (c < NN && r < NN) {
            int slot = atomicAdd(&cursor[c], 1);
            if ((unsigned int)slot < NE) csrc[slot] = (int)r;
        }
    }
}

/* aggregate + bias -> fp32 agg. one wave per node, lane owns 4 features.
   h is fp16: 8B gather per lane per edge (halves HBM gather traffic). */
__global__ __launch_bounds__(256) void g_agg(const _Float16* h, const float* dinv,
                                             const int* off, const int* deg,
                                             const int* csrc, const float* pf,
                                             float* agg) {
    int lane = threadIdx.x & 63;
    int n = blockIdx.x * 4 + (threadIdx.x >> 6);
    int f0 = lane * 4;
    float dn = dinv[n];
    float ws = dn * dn;
    const f16x4 hv = *(const f16x4*)(h + (unsigned long long)n * DD + f0);
    float a0 = (float)hv[0] * ws;
    float a1 = (float)hv[1] * ws;
    float a2 = (float)hv[2] * ws;
    float a3 = (float)hv[3] * ws;
    int s = off[n];
    int cnt = deg[n];
    int i = 0;
    for (; i + 1 < cnt; i += 2) {
        int s1 = csrc[s + i];
        int s2 = csrc[s + i + 1];
        if ((unsigned int)s1 < NN) {
            float w1 = dinv[s1] * dn;
            f16x4 v1 = *(const f16x4*)(h + (unsigned long long)s1 * DD + f0);
            a0 += (float)v1[0] * w1;
            a1 += (float)v1[1] * w1;
            a2 += (float)v1[2] * w1;
            a3 += (float)v1[3] * w1;
        }
        if ((unsigned int)s2 < NN) {
            float w2 = dinv[s2] * dn;
            f16x4 v2 = *(const f16x4*)(h + (unsigned long long)s2 * DD + f0);
            a0 += (float)v2[0] * w2;
            a1 += (float)v2[1] * w2;
            a2 += (float)v2[2] * w2;
            a3 += (float)v2[3] * w2;
        }
    }
    if (i < cnt) {
        int s1 = csrc[s + i];
        if ((unsigned int)s1 < NN) {
            float w1 = dinv[s1] * dn;
            f16x4 v1 = *(const f16x4*)(h + (unsigned long long)s1 * DD + f0);
            a0 += (float)v1[0] * w1;
            a1 += (float)v1[1] * w1;
            a2 += (float)v1[2] * w1;
            a3 += (float)v1[3] * w1;
        }
    }
    float* op = agg + (unsigned long long)n * DD + f0;
    op[0] = a0 + pf[f0 + 0];
    op[1] = a1 + pf[f0 + 1];
    op[2] = a2 + pf[f0 + 2];
    op[3] = a3 + pf[f0 + 3];
}

__global__ __launch_bounds__(256) void g_stats(const float* agg, float* sums) {
    int t = threadIdx.x;
    float s = 0.f;
    float s2 = 0.f;
    for (int n = blockIdx.x; n < NN; n += 256) {
        float v = agg[(unsigned long long)n * DD + t];
        s += v;
        s2 += v * v;
    }
    atomicAdd(&sums[t], s);
    atomicAdd(&sums[DD + t], s2);
}

__global__ void g_fin(const float* sums, const float* pf, float* ss) {
    int t = threadIdx.x;
    float mean = sums[t] * (1.0f / NN);
    float var = sums[DD + t] * (1.0f / NN) - mean * mean;
    var = fmaxf(var, 0.f);
    float sc = pf[DD + t] * rsqrtf(var + 1e-5f);
    ss[t] = sc;
    ss[DD + t] = pf[2 * DD + t] - mean * sc;
}

/* BN + ReLU: fp32 agg -> FP32 out, float4-vectorized */
__global__ void DenseGCNLayer_2937757631000_kernel(const float* agg, const float* ss,
                                                   float* out) {
    int t = threadIdx.x;
    unsigned long long base = (unsigned long long)blockIdx.x * 1024 + (unsigned int)t * 4;
    int f = (int)(base & 255);
    f32x4 v = *(const f32x4*)(agg + base);
    f32x4 o;
    o[0] = fmaxf(ss[f + 0] * v[0] + ss[DD + f + 0], 0.f);
    o[1] = fmaxf(ss[f + 1] * v[1] + ss[DD + f + 1], 0.f);
    o[2] = fmaxf(ss[f + 2] * v[2] + ss[DD + f + 2], 0.f);
    o[3] = fmaxf(ss[f + 3] * v[3] + ss[DD + f + 3], 0.f);
    *(f32x4*)(out + base) = o;
}

extern "C" void kernel_launch(void* const* d_in, const int* in_sizes, int n_in,
                              void* d_out, int out_size, void* d_ws, size_t ws_size,
                              hipStream_t stream) {
    const void* x = d_in[0];
    const int* ei = (const int*)d_in[1];
    const void* W = d_in[2];
    const void* bias = d_in[3];
    const void* gamma = d_in[4];
    const void* beta = d_in[5];
    char* ws = (char*)d_ws;
    float* out = (float*)d_out;

    _Float16* h = (_Float16*)(ws + 0UL);      /* 25.6 MB fp16 (region reserves 51.2) */
    float* agg = (float*)(ws + 51200000UL);   /* 51.2 MB fp32 */
    int* e32 = (int*)(ws + 102400000UL);      /* 6.4 MB */
    int* csrc = (int*)(ws + 108800000UL);     /* 3.2 MB */
    unsigned short* Wb = (unsigned short*)(ws + 112000000UL); /* 128 KB bf16 */
    int* deg = (int*)(ws + 112262144UL);
    float* dinv = (float*)(ws + 112462336UL);
    int* off = (int*)(ws + 112662528UL);
    int* cursor = (int*)(ws + 112862720UL);
    int* bsum = (int*)(ws + 113062912UL);
    int* bbase = (int*)(ws + 113063936UL);
    float* pf = (float*)(ws + 113064960UL);
    float* sums = (float*)(ws + 113068032UL);
    float* ss = (float*)(ws + 113070080UL);
    int* flags = (int*)(ws + 113072128UL);
    const int* erow = e32;
    const int* ecol = e32 + NE;

    if (ws_size < WS_NEED) {
        fprintf(stderr, "R15_WS_SMALL %zu\n", ws_size);
        fflush(stderr);
        return;
    }

    g_zero<<<196, 256, 0, stream>>>(deg, sums);
    g_detect<<<1, 256, 0, stream>>>((const unsigned short*)x, ei, flags);
    g_cvt_ed<<<3125, 256, 0, stream>>>(ei, flags, e32, deg);
    g_cvt_w<<<DD, 256, 0, stream>>>(W, flags, Wb);
    g_cvt_p<<<1, 256, 0, stream>>>(bias, gamma, beta, flags, pf);
    g_gemm_mfma<<<782, 256, 0, stream>>>(x, flags, Wb, h);
    g_scan1<<<196, 256, 0, stream>>>(deg, off, bsum, dinv);
    g_scan2<<<1, 256, 0, stream>>>(bsum, bbase);
    g_scan3<<<196, 256, 0, stream>>>(off, bbase, cursor);
    g_fill<<<3125, 256, 0, stream>>>(erow, ecol, cursor, csrc);
    g_agg<<<12500, 256, 0, stream>>>(h, dinv, off, deg, csrc, pf, agg);
    g_stats<<<256, 256, 0, stream>>>(agg, sums);
    g_fin<<<1, 256, 0, stream>>>(sums, pf, ss);
    DenseGCNLayer_2937757631000_kernel<<<12500, 256, 0, stream>>>(agg, ss, out);
}

// Round 4
// 389.772 us; speedup vs baseline: 1.3971x; 1.0875x over previous
//
#include <hip/hip_runtime.h>
#include <cstdio>

#define NN 50000
#define NE 800000
#define DD 256
#define WS_NEED 113080000UL

__attribute__((constructor)) static void r16_on_load(void) {
    fprintf(stderr, "R16SO_LOADED\n");
    fflush(stderr);
}

__device__ float b2f(unsigned short u) {
    union { unsigned int i; float f; } c;
    c.i = ((unsigned int)u) << 16;
    return c.f;
}
__device__ float clampf(float v) { return fminf(fmaxf(v, -65504.f), 65504.f); }
__device__ float rdF(const void* p, long long idx, int ff) {
    if (ff) return clampf(b2f(((const unsigned short*)p)[idx]));
    return clampf(((const float*)p)[idx]);
}
__device__ unsigned short f2b_rne(float f) {
    union { float f; unsigned int u; } c;
    c.f = f;
    unsigned int r = (c.u + 0x7FFFu + ((c.u >> 16) & 1u)) >> 16;
    return (unsigned short)r;
}

typedef __attribute__((ext_vector_type(8))) short bf16x8;
typedef __attribute__((ext_vector_type(4))) float f32x4;
typedef __attribute__((ext_vector_type(8))) _Float16 f16x8;

/* zero + dtype detect fused. blocks 0..195 zero; block 196 detects. */
__global__ void g_zero(int* deg, float* sums, const unsigned short* xr,
                       const int* ei, int* flags) {
    if (blockIdx.x == 196) {
        __shared__ int acc[2];
        if (threadIdx.x < 2) acc[threadIdx.x] = 0;
        __syncthreads();
        int g = 0;
        for (int j = 0; j < 4; j++) {
            unsigned short u = xr[(threadIdx.x * 4 + j) * 2];
            int e = (u >> 7) & 0xFF;
            if (u == 0 || u == 0x8000 || (e >= 100 && e <= 140)) g++;
        }
        atomicAdd(&acc[0], g);
        if (ei[2 * threadIdx.x + 1] != 0) atomicAdd(&acc[1], 1);
        __syncthreads();
        if (threadIdx.x == 0) {
            flags[0] = (acc[0] >= 922) ? 1 : 0; /* 1 => bf16 floats */
            flags[1] = (acc[1] == 0) ? 1 : 0;   /* 1 => int64 edges */
        }
        return;
    }
    int i = blockIdx.x * 256 + threadIdx.x;
    if (i < NN) deg[i] = 0;
    if (i < 2 * DD) sums[i] = 0.f;
}

/* fused edge convert + degree count (one pass over raw edges) */
__global__ void g_cvt_ed(const int* raw, const int* flags, int* e32, int* deg) {
    int e = blockIdx.x * 256 + threadIdx.x;
    if (e >= NE) return;
    int f = flags[1];
    int r = f ? raw[2 * e] : raw[e];
    int c = f ? raw[2 * (NE + e)] : raw[NE + e];
    e32[e] = r;
    e32[NE + e] = c;
    if ((unsigned int)r < NN && (unsigned int)c < NN) atomicAdd(&deg[c], 1);
}

/* W -> bf16 [o][k]; block 256 converts bias/gamma/beta params */
__global__ void g_cvt_w(const void* W, const void* bias, const void* gamma,
                        const void* beta, const int* flags, unsigned short* Wb,
                        float* pf) {
    int ff = flags[0];
    int t = threadIdx.x;
    if (blockIdx.x == 256) {
        pf[t] = rdF(bias, t, ff);
        pf[DD + t] = rdF(gamma, t, ff);
        pf[2 * DD + t] = rdF(beta, t, ff);
        return;
    }
    int i = blockIdx.x * 256 + t;
    Wb[i] = f2b_rne(rdF(W, i, ff));
}

/* scan1 also emits dinv */
__global__ __launch_bounds__(256) void g_scan1(const int* deg, int* off, int* bsum,
                                               float* dinv) {
    __shared__ int sm[256];
    int tid = threadIdx.x;
    int i = blockIdx.x * 256 + tid;
    int v = (i < NN) ? deg[i] : 0;
    sm[tid] = v;
    __syncthreads();
    for (int s = 1; s < 256; s <<= 1) {
        int t = (tid >= s) ? sm[tid - s] : 0;
        __syncthreads();
        sm[tid] += t;
        __syncthreads();
    }
    if (i < NN) {
        off[i] = sm[tid] - v;
        dinv[i] = rsqrtf((float)(v + 1));
    }
    if (tid == 255) bsum[blockIdx.x] = sm[255];
}

__global__ __launch_bounds__(256) void g_scan2(const int* bsum, int* bbase) {
    __shared__ int sm[256];
    int tid = threadIdx.x;
    int v = (tid < 196) ? bsum[tid] : 0;
    sm[tid] = v;
    __syncthreads();
    for (int s = 1; s < 256; s <<= 1) {
        int t = (tid >= s) ? sm[tid - s] : 0;
        __syncthreads();
        sm[tid] += t;
        __syncthreads();
    }
    if (tid < 196) bbase[tid] = sm[tid] - v;
}

__global__ void g_scan3(int* off, const int* bbase, int* cursor) {
    int i = blockIdx.x * 256 + threadIdx.x;
    if (i < NN) {
        int o = off[i] + bbase[i >> 8];
        off[i] = o;
        cursor[i] = o;
    }
}

/* MFMA GEMM: h'[n][o] = dinv[n] * sum_k x[n][k]*W[o][k], fp32 acc, fp16 store.
   C/D: col = lane&15, row = (lane>>4)*4 + reg  (m89-verified mapping) */
__global__ __launch_bounds__(256) void g_gemm_mfma(const void* x, const int* flags,
                                                   const unsigned short* Wb,
                                                   const float* dinv, _Float16* h) {
    int wave = threadIdx.x >> 6;
    int lane = threadIdx.x & 63;
    int gw = blockIdx.x * 4 + wave;
    if (gw >= 3125) return;
    int r0 = gw * 16;
    int l15 = lane & 15;
    int kq = lane >> 4;

    bf16x8 a[8];
    int ff = flags[0];
    if (ff) {
        const unsigned short* p =
            (const unsigned short*)x + (unsigned long long)(r0 + l15) * DD + kq * 8;
#pragma unroll
        for (int k = 0; k < 8; k++)
            a[k] = *(const bf16x8*)(p + k * 32);
    } else {
        const float* p = (const float*)x + (unsigned long long)(r0 + l15) * DD + kq * 8;
#pragma unroll
        for (int k = 0; k < 8; k++) {
#pragma unroll
            for (int j = 0; j < 8; j++)
                a[k][j] = (short)f2b_rne(p[k * 32 + j]);
        }
    }

    float dv[4];
#pragma unroll
    for (int j = 0; j < 4; j++) dv[j] = dinv[r0 + kq * 4 + j];

#pragma unroll
    for (int ct = 0; ct < 16; ct++) {
        const unsigned short* q = Wb + (unsigned long long)(ct * 16 + l15) * DD + kq * 8;
        f32x4 acc = {0.f, 0.f, 0.f, 0.f};
#pragma unroll
        for (int k = 0; k < 8; k++) {
            bf16x8 b = *(const bf16x8*)(q + k * 32);
            acc = __builtin_amdgcn_mfma_f32_16x16x32_bf16(a[k], b, acc, 0, 0, 0);
        }
        _Float16* op = h + (unsigned long long)(r0 + kq * 4) * DD + ct * 16 + l15;
#pragma unroll
        for (int j = 0; j < 4; j++)
            op[(unsigned long long)j * DD] = (_Float16)(acc[j] * dv[j]);
    }
}

__global__ void g_fill(const int* erow, const int* ecol, int* cursor, int* csrc) {
    int e = blockIdx.x * 256 + threadIdx.x;
    if (e < NE) {
        unsigned int c = (unsigned int)ecol[e];
        unsigned int r = (unsigned int)erow[e];
        if (c < NN && r < NN) {
            int slot = atomicAdd(&cursor[c], 1);
            if ((unsigned int)slot < NE) csrc[slot] = (int)r;
        }
    }
}

/* aggregate + bias + fused stats. 16 nodes/block, 4 waves, 4 nodes/wave.
   Half-wave per edge: 32 lanes x f16x8 = one 512B h' row per half-wave.
   agg[n] = dn*(h'[n] + sum h'[src]) + bias; stats on fp32, agg stored fp16. */
__global__ __launch_bounds__(256) void g_agg(const _Float16* h, const float* dinv,
                                             const int* off, const int* deg,
                                             const int* csrc, const float* pf,
                                             _Float16* agg, float* sums) {
    __shared__ float lsum[2][DD];
    int tid = threadIdx.x;
    lsum[0][tid] = 0.f;
    lsum[1][tid] = 0.f;
    int wave = tid >> 6;
    int lane = tid & 63;
    int half = lane >> 5;
    int fl = (lane & 31) * 8;
    float bias_[8];
#pragma unroll
    for (int j = 0; j < 8; j++) bias_[j] = pf[fl + j];
    float st[8], st2[8];
#pragma unroll
    for (int j = 0; j < 8; j++) { st[j] = 0.f; st2[j] = 0.f; }
    __syncthreads();

    for (int t = 0; t < 4; t++) {
        int n = blockIdx.x * 16 + wave * 4 + t;
        float dn = dinv[n];
        float acc[8];
        if (half == 0) {
            f16x8 v = *(const f16x8*)(h + (unsigned long long)n * DD + fl);
#pragma unroll
            for (int j = 0; j < 8; j++) acc[j] = (float)v[j];
        } else {
#pragma unroll
            for (int j = 0; j < 8; j++) acc[j] = 0.f;
        }
        int s = off[n];
        int cnt = deg[n];
        int mycnt = (cnt - half + 1) >> 1; /* edges with index === half (mod 2) */
        const int* ip = csrc + s + half;
        int k = 0;
        for (; k + 4 <= mycnt; k += 4) {
            int s0 = ip[2 * k];
            int s1 = ip[2 * k + 2];
            int s2 = ip[2 * k + 4];
            int s3 = ip[2 * k + 6];
            f16x8 v0 = *(const f16x8*)(h + (unsigned long long)s0 * DD + fl);
            f16x8 v1 = *(const f16x8*)(h + (unsigned long long)s1 * DD + fl);
            f16x8 v2 = *(const f16x8*)(h + (unsigned long long)s2 * DD + fl);
            f16x8 v3 = *(const f16x8*)(h + (unsigned long long)s3 * DD + fl);
#pragma unroll
            for (int j = 0; j < 8; j++)
                acc[j] += ((float)v0[j] + (float)v1[j]) + ((float)v2[j] + (float)v3[j]);
        }
        for (; k < mycnt; k++) {
            int s0 = ip[2 * k];
            f16x8 v0 = *(const f16x8*)(h + (unsigned long long)s0 * DD + fl);
#pragma unroll
            for (int j = 0; j < 8; j++) acc[j] += (float)v0[j];
        }
#pragma unroll
        for (int j = 0; j < 8; j++) acc[j] += __shfl_xor(acc[j], 32, 64);
        if (half == 0) {
            f16x8 o;
#pragma unroll
            for (int j = 0; j < 8; j++) {
                float v = dn * acc[j] + bias_[j];
                st[j] += v;
                st2[j] += v * v;
                o[j] = (_Float16)v;
            }
            *(f16x8*)(agg + (unsigned long long)n * DD + fl) = o;
        }
    }
    if (half == 0) {
#pragma unroll
        for (int j = 0; j < 8; j++) {
            atomicAdd(&lsum[0][fl + j], st[j]);
            atomicAdd(&lsum[1][fl + j], st2[j]);
        }
    }
    __syncthreads();
    atomicAdd(&sums[tid], lsum[0][tid]);
    atomicAdd(&sums[DD + tid], lsum[1][tid]);
}

__global__ void g_fin(const float* sums, const float* pf, float* ss) {
    int t = threadIdx.x;
    float mean = sums[t] * (1.0f / NN);
    float var = sums[DD + t] * (1.0f / NN) - mean * mean;
    var = fmaxf(var, 0.f);
    float sc = pf[DD + t] * rsqrtf(var + 1e-5f);
    ss[t] = sc;
    ss[DD + t] = pf[2 * DD + t] - mean * sc;
}

/* BN + ReLU: fp16 agg -> fp32 out. 8 elems/thread, grid 6250. */
__global__ void DenseGCNLayer_2937757631000_kernel(const _Float16* agg, const float* ss,
                                                   float* out) {
    int t = threadIdx.x;
    unsigned long long base =
        (unsigned long long)blockIdx.x * 2048 + (unsigned int)t * 8;
    int f = (int)(base & 255);
    f16x8 v = *(const f16x8*)(agg + base);
    f32x4 o0, o1;
#pragma unroll
    for (int j = 0; j < 4; j++)
        o0[j] = fmaxf(ss[f + j] * (float)v[j] + ss[DD + f + j], 0.f);
#pragma unroll
    for (int j = 0; j < 4; j++)
        o1[j] = fmaxf(ss[f + 4 + j] * (float)v[4 + j] + ss[DD + f + 4 + j], 0.f);
    *(f32x4*)(out + base) = o0;
    *(f32x4*)(out + base + 4) = o1;
}

extern "C" void kernel_launch(void* const* d_in, const int* in_sizes, int n_in,
                              void* d_out, int out_size, void* d_ws, size_t ws_size,
                              hipStream_t stream) {
    const void* x = d_in[0];
    const int* ei = (const int*)d_in[1];
    const void* W = d_in[2];
    const void* bias = d_in[3];
    const void* gamma = d_in[4];
    const void* beta = d_in[5];
    char* ws = (char*)d_ws;
    float* out = (float*)d_out;

    _Float16* h = (_Float16*)(ws + 0UL);        /* 25.6 MB fp16 */
    _Float16* agg = (_Float16*)(ws + 51200000UL); /* 25.6 MB fp16 */
    int* e32 = (int*)(ws + 102400000UL);        /* 6.4 MB */
    int* csrc = (int*)(ws + 108800000UL);       /* 3.2 MB */
    unsigned short* Wb = (unsigned short*)(ws + 112000000UL); /* 128 KB bf16 */
    int* deg = (int*)(ws + 112262144UL);
    float* dinv = (float*)(ws + 112462336UL);
    int* off = (int*)(ws + 112662528UL);
    int* cursor = (int*)(ws + 112862720UL);
    int* bsum = (int*)(ws + 113062912UL);
    int* bbase = (int*)(ws + 113063936UL);
    float* pf = (float*)(ws + 113064960UL);
    float* sums = (float*)(ws + 113068032UL);
    float* ss = (float*)(ws + 113070080UL);
    int* flags = (int*)(ws + 113072128UL);
    const int* erow = e32;
    const int* ecol = e32 + NE;

    if (ws_size < WS_NEED) {
        fprintf(stderr, "R16_WS_SMALL %zu\n", ws_size);
        fflush(stderr);
        return;
    }

    g_zero<<<197, 256, 0, stream>>>(deg, sums, (const unsigned short*)x, ei, flags);
    g_cvt_ed<<<3125, 256, 0, stream>>>(ei, flags, e32, deg);
    g_cvt_w<<<257, 256, 0, stream>>>(W, bias, gamma, beta, flags, Wb, pf);
    g_scan1<<<196, 256, 0, stream>>>(deg, off, bsum, dinv);
    g_scan2<<<1, 256, 0, stream>>>(bsum, bbase);
    g_scan3<<<196, 256, 0, stream>>>(off, bbase, cursor);
    g_gemm_mfma<<<782, 256, 0, stream>>>(x, flags, Wb, dinv, h);
    g_fill<<<3125, 256, 0, stream>>>(erow, ecol, cursor, csrc);
    g_agg<<<3125, 256, 0, stream>>>(h, dinv, off, deg, csrc, pf, agg, sums);
    g_fin<<<1, 256, 0, stream>>>(sums, pf, ss);
    DenseGCNLayer_2937757631000_kernel<<<6250, 256, 0, stream>>>(agg, ss, out);
}

// Round 5
// 382.676 us; speedup vs baseline: 1.4230x; 1.0185x over previous
//
#include <hip/hip_runtime.h>
#include <cstdio>

#define NN 50000
#define NE 800000
#define DD 256
#define WS_NEED 113080000UL

__attribute__((constructor)) static void r17_on_load(void) {
    fprintf(stderr, "R17SO_LOADED\n");
    fflush(stderr);
}

__device__ float b2f(unsigned short u) {
    union { unsigned int i; float f; } c;
    c.i = ((unsigned int)u) << 16;
    return c.f;
}
__device__ float clampf(float v) { return fminf(fmaxf(v, -65504.f), 65504.f); }
__device__ float rdF(const void* p, long long idx, int ff) {
    if (ff) return clampf(b2f(((const unsigned short*)p)[idx]));
    return clampf(((const float*)p)[idx]);
}
__device__ unsigned short f2b_rne(float f) {
    union { float f; unsigned int u; } c;
    c.f = f;
    unsigned int r = (c.u + 0x7FFFu + ((c.u >> 16) & 1u)) >> 16;
    return (unsigned short)r;
}

typedef __attribute__((ext_vector_type(8))) short bf16x8;
typedef __attribute__((ext_vector_type(4))) float f32x4;
typedef __attribute__((ext_vector_type(4))) _Float16 f16x4;
typedef __attribute__((ext_vector_type(8))) _Float16 f16x8;

/* zero + dtype detect fused. blocks 0..195 zero; block 196 detects. */
__global__ void g_zero(int* deg, float* sums, const unsigned short* xr,
                       const int* ei, int* flags) {
    if (blockIdx.x == 196) {
        __shared__ int acc[2];
        if (threadIdx.x < 2) acc[threadIdx.x] = 0;
        __syncthreads();
        int g = 0;
        for (int j = 0; j < 4; j++) {
            unsigned short u = xr[(threadIdx.x * 4 + j) * 2];
            int e = (u >> 7) & 0xFF;
            if (u == 0 || u == 0x8000 || (e >= 100 && e <= 140)) g++;
        }
        atomicAdd(&acc[0], g);
        if (ei[2 * threadIdx.x + 1] != 0) atomicAdd(&acc[1], 1);
        __syncthreads();
        if (threadIdx.x == 0) {
            flags[0] = (acc[0] >= 922) ? 1 : 0; /* 1 => bf16 floats */
            flags[1] = (acc[1] == 0) ? 1 : 0;   /* 1 => int64 edges */
        }
        return;
    }
    int i = blockIdx.x * 256 + threadIdx.x;
    if (i < NN) deg[i] = 0;
    if (i < 2 * DD) sums[i] = 0.f;
}

/* fused edge convert + degree count (one pass over raw edges) */
__global__ void g_cvt_ed(const int* raw, const int* flags, int* e32, int* deg) {
    int e = blockIdx.x * 256 + threadIdx.x;
    if (e >= NE) return;
    int f = flags[1];
    int r = f ? raw[2 * e] : raw[e];
    int c = f ? raw[2 * (NE + e)] : raw[NE + e];
    e32[e] = r;
    e32[NE + e] = c;
    if ((unsigned int)r < NN && (unsigned int)c < NN) atomicAdd(&deg[c], 1);
}

/* W -> bf16 [o][k]; block 256 converts bias/gamma/beta params */
__global__ void g_cvt_w(const void* W, const void* bias, const void* gamma,
                        const void* beta, const int* flags, unsigned short* Wb,
                        float* pf) {
    int ff = flags[0];
    int t = threadIdx.x;
    if (blockIdx.x == 256) {
        pf[t] = rdF(bias, t, ff);
        pf[DD + t] = rdF(gamma, t, ff);
        pf[2 * DD + t] = rdF(beta, t, ff);
        return;
    }
    int i = blockIdx.x * 256 + t;
    Wb[i] = f2b_rne(rdF(W, i, ff));
}

/* scan1 also emits dinv */
__global__ __launch_bounds__(256) void g_scan1(const int* deg, int* off, int* bsum,
                                               float* dinv) {
    __shared__ int sm[256];
    int tid = threadIdx.x;
    int i = blockIdx.x * 256 + tid;
    int v = (i < NN) ? deg[i] : 0;
    sm[tid] = v;
    __syncthreads();
    for (int s = 1; s < 256; s <<= 1) {
        int t = (tid >= s) ? sm[tid - s] : 0;
        __syncthreads();
        sm[tid] += t;
        __syncthreads();
    }
    if (i < NN) {
        off[i] = sm[tid] - v;
        dinv[i] = rsqrtf((float)(v + 1));
    }
    if (tid == 255) bsum[blockIdx.x] = sm[255];
}

__global__ __launch_bounds__(256) void g_scan2(const int* bsum, int* bbase) {
    __shared__ int sm[256];
    int tid = threadIdx.x;
    int v = (tid < 196) ? bsum[tid] : 0;
    sm[tid] = v;
    __syncthreads();
    for (int s = 1; s < 256; s <<= 1) {
        int t = (tid >= s) ? sm[tid - s] : 0;
        __syncthreads();
        sm[tid] += t;
        __syncthreads();
    }
    if (tid < 196) bbase[tid] = sm[tid] - v;
}

__global__ void g_scan3(int* off, const int* bbase, int* cursor) {
    int i = blockIdx.x * 256 + threadIdx.x;
    if (i < NN) {
        int o = off[i] + bbase[i >> 8];
        off[i] = o;
        cursor[i] = o;
    }
}

/* MFMA GEMM: h'[n][o] = dinv[n] * sum_k x[n][k]*W[o][k], fp32 acc, fp16 store.
   C/D: col = lane&15, row = (lane>>4)*4 + reg  (m89-verified mapping) */
__global__ __launch_bounds__(256) void g_gemm_mfma(const void* x, const int* flags,
                                                   const unsigned short* Wb,
                                                   const float* dinv, _Float16* h) {
    int wave = threadIdx.x >> 6;
    int lane = threadIdx.x & 63;
    int gw = blockIdx.x * 4 + wave;
    if (gw >= 3125) return;
    int r0 = gw * 16;
    int l15 = lane & 15;
    int kq = lane >> 4;

    bf16x8 a[8];
    int ff = flags[0];
    if (ff) {
        const unsigned short* p =
            (const unsigned short*)x + (unsigned long long)(r0 + l15) * DD + kq * 8;
#pragma unroll
        for (int k = 0; k < 8; k++)
            a[k] = *(const bf16x8*)(p + k * 32);
    } else {
        const float* p = (const float*)x + (unsigned long long)(r0 + l15) * DD + kq * 8;
#pragma unroll
        for (int k = 0; k < 8; k++) {
#pragma unroll
            for (int j = 0; j < 8; j++)
                a[k][j] = (short)f2b_rne(p[k * 32 + j]);
        }
    }

    float dv[4];
#pragma unroll
    for (int j = 0; j < 4; j++) dv[j] = dinv[r0 + kq * 4 + j];

#pragma unroll
    for (int ct = 0; ct < 16; ct++) {
        const unsigned short* q = Wb + (unsigned long long)(ct * 16 + l15) * DD + kq * 8;
        f32x4 acc = {0.f, 0.f, 0.f, 0.f};
#pragma unroll
        for (int k = 0; k < 8; k++) {
            bf16x8 b = *(const bf16x8*)(q + k * 32);
            acc = __builtin_amdgcn_mfma_f32_16x16x32_bf16(a[k], b, acc, 0, 0, 0);
        }
        _Float16* op = h + (unsigned long long)(r0 + kq * 4) * DD + ct * 16 + l15;
#pragma unroll
        for (int j = 0; j < 4; j++)
            op[(unsigned long long)j * DD] = (_Float16)(acc[j] * dv[j]);
    }
}

__global__ void g_fill(const int* erow, const int* ecol, int* cursor, int* csrc) {
    int e = blockIdx.x * 256 + threadIdx.x;
    if (e < NE) {
        unsigned int c = (unsigned int)ecol[e];
        unsigned int r = (unsigned int)erow[e];
        if (c < NN && r < NN) {
            int slot = atomicAdd(&cursor[c], 1);
            if ((unsigned int)slot < NE) csrc[slot] = (int)r;
        }
    }
}

/* aggregate + bias -> fp16 agg. one node per wave, lane owns 4 features.
   agg[n] = dn*(h'[n] + sum h'[src]) + bias, h' pre-scaled by dinv in GEMM.
   8-deep unroll: 8 independent 512B row loads in flight per wave. */
__global__ __launch_bounds__(256) void g_agg(const _Float16* h, const float* dinv,
                                             const int* off, const int* deg,
                                             const int* csrc, const float* pf,
                                             _Float16* agg) {
    int lane = threadIdx.x & 63;
    int n = blockIdx.x * 4 + (threadIdx.x >> 6);
    int f0 = lane * 4;
    int s = __builtin_amdgcn_readfirstlane(off[n]);
    int cnt = __builtin_amdgcn_readfirstlane(deg[n]);
    float dn = dinv[n];
    f16x4 hv = *(const f16x4*)(h + (unsigned long long)n * DD + f0);
    float a0 = (float)hv[0];
    float a1 = (float)hv[1];
    float a2 = (float)hv[2];
    float a3 = (float)hv[3];
    const int* ip = csrc + s;
    int k = 0;
    for (; k + 8 <= cnt; k += 8) {
        int i0 = ip[k + 0], i1 = ip[k + 1], i2 = ip[k + 2], i3 = ip[k + 3];
        int i4 = ip[k + 4], i5 = ip[k + 5], i6 = ip[k + 6], i7 = ip[k + 7];
        f16x4 v0 = *(const f16x4*)(h + (unsigned long long)i0 * DD + f0);
        f16x4 v1 = *(const f16x4*)(h + (unsigned long long)i1 * DD + f0);
        f16x4 v2 = *(const f16x4*)(h + (unsigned long long)i2 * DD + f0);
        f16x4 v3 = *(const f16x4*)(h + (unsigned long long)i3 * DD + f0);
        f16x4 v4 = *(const f16x4*)(h + (unsigned long long)i4 * DD + f0);
        f16x4 v5 = *(const f16x4*)(h + (unsigned long long)i5 * DD + f0);
        f16x4 v6 = *(const f16x4*)(h + (unsigned long long)i6 * DD + f0);
        f16x4 v7 = *(const f16x4*)(h + (unsigned long long)i7 * DD + f0);
        a0 += (((float)v0[0] + (float)v1[0]) + ((float)v2[0] + (float)v3[0])) +
              (((float)v4[0] + (float)v5[0]) + ((float)v6[0] + (float)v7[0]));
        a1 += (((float)v0[1] + (float)v1[1]) + ((float)v2[1] + (float)v3[1])) +
              (((float)v4[1] + (float)v5[1]) + ((float)v6[1] + (float)v7[1]));
        a2 += (((float)v0[2] + (float)v1[2]) + ((float)v2[2] + (float)v3[2])) +
              (((float)v4[2] + (float)v5[2]) + ((float)v6[2] + (float)v7[2]));
        a3 += (((float)v0[3] + (float)v1[3]) + ((float)v2[3] + (float)v3[3])) +
              (((float)v4[3] + (float)v5[3]) + ((float)v6[3] + (float)v7[3]));
    }
    for (; k + 4 <= cnt; k += 4) {
        int i0 = ip[k + 0], i1 = ip[k + 1], i2 = ip[k + 2], i3 = ip[k + 3];
        f16x4 v0 = *(const f16x4*)(h + (unsigned long long)i0 * DD + f0);
        f16x4 v1 = *(const f16x4*)(h + (unsigned long long)i1 * DD + f0);
        f16x4 v2 = *(const f16x4*)(h + (unsigned long long)i2 * DD + f0);
        f16x4 v3 = *(const f16x4*)(h + (unsigned long long)i3 * DD + f0);
        a0 += ((float)v0[0] + (float)v1[0]) + ((float)v2[0] + (float)v3[0]);
        a1 += ((float)v0[1] + (float)v1[1]) + ((float)v2[1] + (float)v3[1]);
        a2 += ((float)v0[2] + (float)v1[2]) + ((float)v2[2] + (float)v3[2]);
        a3 += ((float)v0[3] + (float)v1[3]) + ((float)v2[3] + (float)v3[3]);
    }
    for (; k < cnt; k++) {
        int i0 = ip[k];
        f16x4 v0 = *(const f16x4*)(h + (unsigned long long)i0 * DD + f0);
        a0 += (float)v0[0];
        a1 += (float)v0[1];
        a2 += (float)v0[2];
        a3 += (float)v0[3];
    }
    f16x4 o;
    o[0] = (_Float16)(dn * a0 + pf[f0 + 0]);
    o[1] = (_Float16)(dn * a1 + pf[f0 + 1]);
    o[2] = (_Float16)(dn * a2 + pf[f0 + 2]);
    o[3] = (_Float16)(dn * a3 + pf[f0 + 3]);
    *(f16x4*)(agg + (unsigned long long)n * DD + f0) = o;
}

/* stats over fp16 agg */
__global__ __launch_bounds__(256) void g_stats(const _Float16* agg, float* sums) {
    int t = threadIdx.x;
    float s = 0.f;
    float s2 = 0.f;
    for (int n = blockIdx.x; n < NN; n += 256) {
        float v = (float)agg[(unsigned long long)n * DD + t];
        s += v;
        s2 += v * v;
    }
    atomicAdd(&sums[t], s);
    atomicAdd(&sums[DD + t], s2);
}

__global__ void g_fin(const float* sums, const float* pf, float* ss) {
    int t = threadIdx.x;
    float mean = sums[t] * (1.0f / NN);
    float var = sums[DD + t] * (1.0f / NN) - mean * mean;
    var = fmaxf(var, 0.f);
    float sc = pf[DD + t] * rsqrtf(var + 1e-5f);
    ss[t] = sc;
    ss[DD + t] = pf[2 * DD + t] - mean * sc;
}

/* BN + ReLU: fp16 agg -> fp32 out. 8 elems/thread, grid 6250. */
__global__ void DenseGCNLayer_2937757631000_kernel(const _Float16* agg, const float* ss,
                                                   float* out) {
    int t = threadIdx.x;
    unsigned long long base =
        (unsigned long long)blockIdx.x * 2048 + (unsigned int)t * 8;
    int f = (int)(base & 255);
    f16x8 v = *(const f16x8*)(agg + base);
    f32x4 o0, o1;
#pragma unroll
    for (int j = 0; j < 4; j++)
        o0[j] = fmaxf(ss[f + j] * (float)v[j] + ss[DD + f + j], 0.f);
#pragma unroll
    for (int j = 0; j < 4; j++)
        o1[j] = fmaxf(ss[f + 4 + j] * (float)v[4 + j] + ss[DD + f + 4 + j], 0.f);
    *(f32x4*)(out + base) = o0;
    *(f32x4*)(out + base + 4) = o1;
}

extern "C" void kernel_launch(void* const* d_in, const int* in_sizes, int n_in,
                              void* d_out, int out_size, void* d_ws, size_t ws_size,
                              hipStream_t stream) {
    const void* x = d_in[0];
    const int* ei = (const int*)d_in[1];
    const void* W = d_in[2];
    const void* bias = d_in[3];
    const void* gamma = d_in[4];
    const void* beta = d_in[5];
    char* ws = (char*)d_ws;
    float* out = (float*)d_out;

    _Float16* h = (_Float16*)(ws + 0UL);          /* 25.6 MB fp16 */
    _Float16* agg = (_Float16*)(ws + 51200000UL); /* 25.6 MB fp16 */
    int* e32 = (int*)(ws + 102400000UL);          /* 6.4 MB */
    int* csrc = (int*)(ws + 108800000UL);         /* 3.2 MB */
    unsigned short* Wb = (unsigned short*)(ws + 112000000UL); /* 128 KB bf16 */
    int* deg = (int*)(ws + 112262144UL);
    float* dinv = (float*)(ws + 112462336UL);
    int* off = (int*)(ws + 112662528UL);
    int* cursor = (int*)(ws + 112862720UL);
    int* bsum = (int*)(ws + 113062912UL);
    int* bbase = (int*)(ws + 113063936UL);
    float* pf = (float*)(ws + 113064960UL);
    float* sums = (float*)(ws + 113068032UL);
    float* ss = (float*)(ws + 113070080UL);
    int* flags = (int*)(ws + 113072128UL);
    const int* erow = e32;
    const int* ecol = e32 + NE;

    if (ws_size < WS_NEED) {
        fprintf(stderr, "R17_WS_SMALL %zu\n", ws_size);
        fflush(stderr);
        return;
    }

    g_zero<<<197, 256, 0, stream>>>(deg, sums, (const unsigned short*)x, ei, flags);
    g_cvt_ed<<<3125, 256, 0, stream>>>(ei, flags, e32, deg);
    g_cvt_w<<<257, 256, 0, stream>>>(W, bias, gamma, beta, flags, Wb, pf);
    g_scan1<<<196, 256, 0, stream>>>(deg, off, bsum, dinv);
    g_scan2<<<1, 256, 0, stream>>>(bsum, bbase);
    g_scan3<<<196, 256, 0, stream>>>(off, bbase, cursor);
    g_gemm_mfma<<<782, 256, 0, stream>>>(x, flags, Wb, dinv, h);
    g_fill<<<3125, 256, 0, stream>>>(erow, ecol, cursor, csrc);
    g_agg<<<12500, 256, 0, stream>>>(h, dinv, off, deg, csrc, pf, agg);
    g_stats<<<256, 256, 0, stream>>>(agg, sums);
    g_fin<<<1, 256, 0, stream>>>(sums, pf, ss);
    DenseGCNLayer_2937757631000_kernel<<<6250, 256, 0, stream>>>(agg, ss, out);
}

// Round 6
// 380.161 us; speedup vs baseline: 1.4324x; 1.0066x over previous
//
#include <hip/hip_runtime.h>
#include <cstdio>

#define NN 50000
#define NE 800000
#define DD 256
#define WS_NEED 113080000UL

__attribute__((constructor)) static void r18_on_load(void) {
    fprintf(stderr, "R18SO_LOADED\n");
    fflush(stderr);
}

__device__ float b2f(unsigned short u) {
    union { unsigned int i; float f; } c;
    c.i = ((unsigned int)u) << 16;
    return c.f;
}
__device__ float clampf(float v) { return fminf(fmaxf(v, -65504.f), 65504.f); }
__device__ float rdF(const void* p, long long idx, int ff) {
    if (ff) return clampf(b2f(((const unsigned short*)p)[idx]));
    return clampf(((const float*)p)[idx]);
}
__device__ unsigned short f2b_rne(float f) {
    union { float f; unsigned int u; } c;
    c.f = f;
    unsigned int r = (c.u + 0x7FFFu + ((c.u >> 16) & 1u)) >> 16;
    return (unsigned short)r;
}

typedef __attribute__((ext_vector_type(8))) short bf16x8;
typedef __attribute__((ext_vector_type(4))) float f32x4;
typedef __attribute__((ext_vector_type(4))) _Float16 f16x4;
typedef __attribute__((ext_vector_type(8))) _Float16 f16x8;

/* zero + dtype detect fused. blocks 0..195 zero; block 196 detects. */
__global__ void g_zero(int* deg, float* sums, const unsigned short* xr,
                       const int* ei, int* flags) {
    if (blockIdx.x == 196) {
        __shared__ int acc[2];
        if (threadIdx.x < 2) acc[threadIdx.x] = 0;
        __syncthreads();
        int g = 0;
        for (int j = 0; j < 4; j++) {
            unsigned short u = xr[(threadIdx.x * 4 + j) * 2];
            int e = (u >> 7) & 0xFF;
            if (u == 0 || u == 0x8000 || (e >= 100 && e <= 140)) g++;
        }
        atomicAdd(&acc[0], g);
        if (ei[2 * threadIdx.x + 1] != 0) atomicAdd(&acc[1], 1);
        __syncthreads();
        if (threadIdx.x == 0) {
            flags[0] = (acc[0] >= 922) ? 1 : 0; /* 1 => bf16 floats */
            flags[1] = (acc[1] == 0) ? 1 : 0;   /* 1 => int64 edges */
        }
        return;
    }
    int i = blockIdx.x * 256 + threadIdx.x;
    if (i < NN) deg[i] = 0;
    if (i < 2 * DD) sums[i] = 0.f;
}

/* fused edge convert + degree count (one pass over raw edges) */
__global__ void g_cvt_ed(const int* raw, const int* flags, int* e32, int* deg) {
    int e = blockIdx.x * 256 + threadIdx.x;
    if (e >= NE) return;
    int f = flags[1];
    int r = f ? raw[2 * e] : raw[e];
    int c = f ? raw[2 * (NE + e)] : raw[NE + e];
    e32[e] = r;
    e32[NE + e] = c;
    if ((unsigned int)r < NN && (unsigned int)c < NN) atomicAdd(&deg[c], 1);
}

/* W -> bf16 [o][k]; block 256 converts bias/gamma/beta params */
__global__ void g_cvt_w(const void* W, const void* bias, const void* gamma,
                        const void* beta, const int* flags, unsigned short* Wb,
                        float* pf) {
    int ff = flags[0];
    int t = threadIdx.x;
    if (blockIdx.x == 256) {
        pf[t] = rdF(bias, t, ff);
        pf[DD + t] = rdF(gamma, t, ff);
        pf[2 * DD + t] = rdF(beta, t, ff);
        return;
    }
    int i = blockIdx.x * 256 + t;
    Wb[i] = f2b_rne(rdF(W, i, ff));
}

/* scan1 also emits dinv */
__global__ __launch_bounds__(256) void g_scan1(const int* deg, int* off, int* bsum,
                                               float* dinv) {
    __shared__ int sm[256];
    int tid = threadIdx.x;
    int i = blockIdx.x * 256 + tid;
    int v = (i < NN) ? deg[i] : 0;
    sm[tid] = v;
    __syncthreads();
    for (int s = 1; s < 256; s <<= 1) {
        int t = (tid >= s) ? sm[tid - s] : 0;
        __syncthreads();
        sm[tid] += t;
        __syncthreads();
    }
    if (i < NN) {
        off[i] = sm[tid] - v;
        dinv[i] = rsqrtf((float)(v + 1));
    }
    if (tid == 255) bsum[blockIdx.x] = sm[255];
}

__global__ __launch_bounds__(256) void g_scan2(const int* bsum, int* bbase) {
    __shared__ int sm[256];
    int tid = threadIdx.x;
    int v = (tid < 196) ? bsum[tid] : 0;
    sm[tid] = v;
    __syncthreads();
    for (int s = 1; s < 256; s <<= 1) {
        int t = (tid >= s) ? sm[tid - s] : 0;
        __syncthreads();
        sm[tid] += t;
        __syncthreads();
    }
    if (tid < 196) bbase[tid] = sm[tid] - v;
}

__global__ void g_scan3(int* off, const int* bbase, int* cursor) {
    int i = blockIdx.x * 256 + threadIdx.x;
    if (i < NN) {
        int o = off[i] + bbase[i >> 8];
        off[i] = o;
        cursor[i] = o;
    }
}

/* MFMA GEMM: h'[n][o] = dinv[n] * sum_k x[n][k]*W[o][k], fp32 acc, fp16 store.
   k-OUTER / ct-INNER: acc[16] live across kernel -> 16 independent MFMA
   chains, 16 B-loads in flight per K-step (R18 fix for the VGPR=36
   serialized schedule that left the wave at cache latency per MFMA).
   C/D: col = lane&15, row = (lane>>4)*4 + reg  (m89-verified mapping) */
__global__ __launch_bounds__(256) void g_gemm_mfma(const void* x, const int* flags,
                                                   const unsigned short* Wb,
                                                   const float* dinv, _Float16* h) {
    int wave = threadIdx.x >> 6;
    int lane = threadIdx.x & 63;
    int gw = blockIdx.x * 4 + wave;
    if (gw >= 3125) return;
    int r0 = gw * 16;
    int l15 = lane & 15;
    int kq = lane >> 4;

    bf16x8 a[8];
    int ff = flags[0];
    if (ff) {
        const unsigned short* p =
            (const unsigned short*)x + (unsigned long long)(r0 + l15) * DD + kq * 8;
#pragma unroll
        for (int k = 0; k < 8; k++)
            a[k] = *(const bf16x8*)(p + k * 32);
    } else {
        const float* p = (const float*)x + (unsigned long long)(r0 + l15) * DD + kq * 8;
#pragma unroll
        for (int k = 0; k < 8; k++) {
#pragma unroll
            for (int j = 0; j < 8; j++)
                a[k][j] = (short)f2b_rne(p[k * 32 + j]);
        }
    }

    float dv[4];
#pragma unroll
    for (int j = 0; j < 4; j++) dv[j] = dinv[r0 + kq * 4 + j];

    f32x4 acc[16];
#pragma unroll
    for (int ct = 0; ct < 16; ct++) acc[ct] = (f32x4){0.f, 0.f, 0.f, 0.f};

    const unsigned short* wbase = Wb + (unsigned long long)l15 * DD + kq * 8;
#pragma unroll
    for (int k = 0; k < 8; k++) {
        bf16x8 b[16];
#pragma unroll
        for (int ct = 0; ct < 16; ct++)
            b[ct] = *(const bf16x8*)(wbase + ct * 16 * DD + k * 32);
#pragma unroll
        for (int ct = 0; ct < 16; ct++)
            acc[ct] = __builtin_amdgcn_mfma_f32_16x16x32_bf16(a[k], b[ct], acc[ct],
                                                              0, 0, 0);
    }

#pragma unroll
    for (int ct = 0; ct < 16; ct++) {
        _Float16* op = h + (unsigned long long)(r0 + kq * 4) * DD + ct * 16 + l15;
#pragma unroll
        for (int j = 0; j < 4; j++)
            op[(unsigned long long)j * DD] = (_Float16)(acc[ct][j] * dv[j]);
    }
}

__global__ void g_fill(const int* erow, const int* ecol, int* cursor, int* csrc) {
    int e = blockIdx.x * 256 + threadIdx.x;
    if (e < NE) {
        unsigned int c = (unsigned int)ecol[e];
        unsigned int r = (unsigned int)erow[e];
        if (c < NN && r < NN) {
            int slot = atomicAdd(&cursor[c], 1);
            if ((unsigned int)slot < NE) csrc[slot] = (int)r;
        }
    }
}

/* aggregate + bias -> fp16 agg. one node per wave, lane owns 4 features.
   agg[n] = dn*(h'[n] + sum h'[src]) + bias, h' pre-scaled by dinv in GEMM.
   8-deep unroll: 8 independent 512B row loads in flight per wave. */
__global__ __launch_bounds__(256) void g_agg(const _Float16* h, const float* dinv,
                                             const int* off, const int* deg,
                                             const int* csrc, const float* pf,
                                             _Float16* agg) {
    int lane = threadIdx.x & 63;
    int n = blockIdx.x * 4 + (threadIdx.x >> 6);
    int f0 = lane * 4;
    int s = __builtin_amdgcn_readfirstlane(off[n]);
    int cnt = __builtin_amdgcn_readfirstlane(deg[n]);
    float dn = dinv[n];
    f16x4 hv = *(const f16x4*)(h + (unsigned long long)n * DD + f0);
    float a0 = (float)hv[0];
    float a1 = (float)hv[1];
    float a2 = (float)hv[2];
    float a3 = (float)hv[3];
    const int* ip = csrc + s;
    int k = 0;
    for (; k + 8 <= cnt; k += 8) {
        int i0 = ip[k + 0], i1 = ip[k + 1], i2 = ip[k + 2], i3 = ip[k + 3];
        int i4 = ip[k + 4], i5 = ip[k + 5], i6 = ip[k + 6], i7 = ip[k + 7];
        f16x4 v0 = *(const f16x4*)(h + (unsigned long long)i0 * DD + f0);
        f16x4 v1 = *(const f16x4*)(h + (unsigned long long)i1 * DD + f0);
        f16x4 v2 = *(const f16x4*)(h + (unsigned long long)i2 * DD + f0);
        f16x4 v3 = *(const f16x4*)(h + (unsigned long long)i3 * DD + f0);
        f16x4 v4 = *(const f16x4*)(h + (unsigned long long)i4 * DD + f0);
        f16x4 v5 = *(const f16x4*)(h + (unsigned long long)i5 * DD + f0);
        f16x4 v6 = *(const f16x4*)(h + (unsigned long long)i6 * DD + f0);
        f16x4 v7 = *(const f16x4*)(h + (unsigned long long)i7 * DD + f0);
        a0 += (((float)v0[0] + (float)v1[0]) + ((float)v2[0] + (float)v3[0])) +
              (((float)v4[0] + (float)v5[0]) + ((float)v6[0] + (float)v7[0]));
        a1 += (((float)v0[1] + (float)v1[1]) + ((float)v2[1] + (float)v3[1])) +
              (((float)v4[1] + (float)v5[1]) + ((float)v6[1] + (float)v7[1]));
        a2 += (((float)v0[2] + (float)v1[2]) + ((float)v2[2] + (float)v3[2])) +
              (((float)v4[2] + (float)v5[2]) + ((float)v6[2] + (float)v7[2]));
        a3 += (((float)v0[3] + (float)v1[3]) + ((float)v2[3] + (float)v3[3])) +
              (((float)v4[3] + (float)v5[3]) + ((float)v6[3] + (float)v7[3]));
    }
    for (; k + 4 <= cnt; k += 4) {
        int i0 = ip[k + 0], i1 = ip[k + 1], i2 = ip[k + 2], i3 = ip[k + 3];
        f16x4 v0 = *(const f16x4*)(h + (unsigned long long)i0 * DD + f0);
        f16x4 v1 = *(const f16x4*)(h + (unsigned long long)i1 * DD + f0);
        f16x4 v2 = *(const f16x4*)(h + (unsigned long long)i2 * DD + f0);
        f16x4 v3 = *(const f16x4*)(h + (unsigned long long)i3 * DD + f0);
        a0 += ((float)v0[0] + (float)v1[0]) + ((float)v2[0] + (float)v3[0]);
        a1 += ((float)v0[1] + (float)v1[1]) + ((float)v2[1] + (float)v3[1]);
        a2 += ((float)v0[2] + (float)v1[2]) + ((float)v2[2] + (float)v3[2]);
        a3 += ((float)v0[3] + (float)v1[3]) + ((float)v2[3] + (float)v3[3]);
    }
    for (; k < cnt; k++) {
        int i0 = ip[k];
        f16x4 v0 = *(const f16x4*)(h + (unsigned long long)i0 * DD + f0);
        a0 += (float)v0[0];
        a1 += (float)v0[1];
        a2 += (float)v0[2];
        a3 += (float)v0[3];
    }
    f16x4 o;
    o[0] = (_Float16)(dn * a0 + pf[f0 + 0]);
    o[1] = (_Float16)(dn * a1 + pf[f0 + 1]);
    o[2] = (_Float16)(dn * a2 + pf[f0 + 2]);
    o[3] = (_Float16)(dn * a3 + pf[f0 + 3]);
    *(f16x4*)(agg + (unsigned long long)n * DD + f0) = o;
}

/* stats over fp16 agg */
__global__ __launch_bounds__(256) void g_stats(const _Float16* agg, float* sums) {
    int t = threadIdx.x;
    float s = 0.f;
    float s2 = 0.f;
    for (int n = blockIdx.x; n < NN; n += 256) {
        float v = (float)agg[(unsigned long long)n * DD + t];
        s += v;
        s2 += v * v;
    }
    atomicAdd(&sums[t], s);
    atomicAdd(&sums[DD + t], s2);
}

__global__ void g_fin(const float* sums, const float* pf, float* ss) {
    int t = threadIdx.x;
    float mean = sums[t] * (1.0f / NN);
    float var = sums[DD + t] * (1.0f / NN) - mean * mean;
    var = fmaxf(var, 0.f);
    float sc = pf[DD + t] * rsqrtf(var + 1e-5f);
    ss[t] = sc;
    ss[DD + t] = pf[2 * DD + t] - mean * sc;
}

/* BN + ReLU: fp16 agg -> fp32 out. 8 elems/thread, grid 6250. */
__global__ void DenseGCNLayer_2937757631000_kernel(const _Float16* agg, const float* ss,
                                                   float* out) {
    int t = threadIdx.x;
    unsigned long long base =
        (unsigned long long)blockIdx.x * 2048 + (unsigned int)t * 8;
    int f = (int)(base & 255);
    f16x8 v = *(const f16x8*)(agg + base);
    f32x4 o0, o1;
#pragma unroll
    for (int j = 0; j < 4; j++)
        o0[j] = fmaxf(ss[f + j] * (float)v[j] + ss[DD + f + j], 0.f);
#pragma unroll
    for (int j = 0; j < 4; j++)
        o1[j] = fmaxf(ss[f + 4 + j] * (float)v[4 + j] + ss[DD + f + 4 + j], 0.f);
    *(f32x4*)(out + base) = o0;
    *(f32x4*)(out + base + 4) = o1;
}

extern "C" void kernel_launch(void* const* d_in, const int* in_sizes, int n_in,
                              void* d_out, int out_size, void* d_ws, size_t ws_size,
                              hipStream_t stream) {
    const void* x = d_in[0];
    const int* ei = (const int*)d_in[1];
    const void* W = d_in[2];
    const void* bias = d_in[3];
    const void* gamma = d_in[4];
    const void* beta = d_in[5];
    char* ws = (char*)d_ws;
    float* out = (float*)d_out;

    _Float16* h = (_Float16*)(ws + 0UL);          /* 25.6 MB fp16 */
    _Float16* agg = (_Float16*)(ws + 51200000UL); /* 25.6 MB fp16 */
    int* e32 = (int*)(ws + 102400000UL);          /* 6.4 MB */
    int* csrc = (int*)(ws + 108800000UL);         /* 3.2 MB */
    unsigned short* Wb = (unsigned short*)(ws + 112000000UL); /* 128 KB bf16 */
    int* deg = (int*)(ws + 112262144UL);
    float* dinv = (float*)(ws + 112462336UL);
    int* off = (int*)(ws + 112662528UL);
    int* cursor = (int*)(ws + 112862720UL);
    int* bsum = (int*)(ws + 113062912UL);
    int* bbase = (int*)(ws + 113063936UL);
    float* pf = (float*)(ws + 113064960UL);
    float* sums = (float*)(ws + 113068032UL);
    float* ss = (float*)(ws + 113070080UL);
    int* flags = (int*)(ws + 113072128UL);
    const int* erow = e32;
    const int* ecol = e32 + NE;

    if (ws_size < WS_NEED) {
        fprintf(stderr, "R18_WS_SMALL %zu\n", ws_size);
        fflush(stderr);
        return;
    }

    g_zero<<<197, 256, 0, stream>>>(deg, sums, (const unsigned short*)x, ei, flags);
    g_cvt_ed<<<3125, 256, 0, stream>>>(ei, flags, e32, deg);
    g_cvt_w<<<257, 256, 0, stream>>>(W, bias, gamma, beta, flags, Wb, pf);
    g_scan1<<<196, 256, 0, stream>>>(deg, off, bsum, dinv);
    g_scan2<<<1, 256, 0, stream>>>(bsum, bbase);
    g_scan3<<<196, 256, 0, stream>>>(off, bbase, cursor);
    g_gemm_mfma<<<782, 256, 0, stream>>>(x, flags, Wb, dinv, h);
    g_fill<<<3125, 256, 0, stream>>>(erow, ecol, cursor, csrc);
    g_agg<<<12500, 256, 0, stream>>>(h, dinv, off, deg, csrc, pf, agg);
    g_stats<<<256, 256, 0, stream>>>(agg, sums);
    g_fin<<<1, 256, 0, stream>>>(sums, pf, ss);
    DenseGCNLayer_2937757631000_kernel<<<6250, 256, 0, stream>>>(agg, ss, out);
}

// Round 7
// 347.469 us; speedup vs baseline: 1.5672x; 1.0941x over previous
//
#include <hip/hip_runtime.h>
#include <cstdio>

#define NN 50000
#define NE 800000
#define DD 256
#define WS_NEED 113080000UL

__attribute__((constructor)) static void r19_on_load(void) {
    fprintf(stderr, "R19SO_LOADED\n");
    fflush(stderr);
}

__device__ float b2f(unsigned short u) {
    union { unsigned int i; float f; } c;
    c.i = ((unsigned int)u) << 16;
    return c.f;
}
__device__ float clampf(float v) { return fminf(fmaxf(v, -65504.f), 65504.f); }
__device__ float rdF(const void* p, long long idx, int ff) {
    if (ff) return clampf(b2f(((const unsigned short*)p)[idx]));
    return clampf(((const float*)p)[idx]);
}
__device__ unsigned short f2b_rne(float f) {
    union { float f; unsigned int u; } c;
    c.f = f;
    unsigned int r = (c.u + 0x7FFFu + ((c.u >> 16) & 1u)) >> 16;
    return (unsigned short)r;
}

typedef __attribute__((ext_vector_type(8))) short bf16x8;
typedef __attribute__((ext_vector_type(4))) float f32x4;
typedef __attribute__((ext_vector_type(4))) _Float16 f16x4;
typedef __attribute__((ext_vector_type(8))) _Float16 f16x8;

/* zero + dtype detect fused. blocks 0..195 zero; block 196 detects. */
__global__ void g_zero(int* deg, float* sums, const unsigned short* xr,
                       const int* ei, int* flags) {
    if (blockIdx.x == 196) {
        __shared__ int acc[2];
        if (threadIdx.x < 2) acc[threadIdx.x] = 0;
        __syncthreads();
        int g = 0;
        for (int j = 0; j < 4; j++) {
            unsigned short u = xr[(threadIdx.x * 4 + j) * 2];
            int e = (u >> 7) & 0xFF;
            if (u == 0 || u == 0x8000 || (e >= 100 && e <= 140)) g++;
        }
        atomicAdd(&acc[0], g);
        if (ei[2 * threadIdx.x + 1] != 0) atomicAdd(&acc[1], 1);
        __syncthreads();
        if (threadIdx.x == 0) {
            flags[0] = (acc[0] >= 922) ? 1 : 0; /* 1 => bf16 floats */
            flags[1] = (acc[1] == 0) ? 1 : 0;   /* 1 => int64 edges */
        }
        return;
    }
    int i = blockIdx.x * 256 + threadIdx.x;
    if (i < NN) deg[i] = 0;
    if (i < 2 * DD) sums[i] = 0.f;
}

/* fused edge convert + degree count (one pass over raw edges) */
__global__ void g_cvt_ed(const int* raw, const int* flags, int* e32, int* deg) {
    int e = blockIdx.x * 256 + threadIdx.x;
    if (e >= NE) return;
    int f = flags[1];
    int r = f ? raw[2 * e] : raw[e];
    int c = f ? raw[2 * (NE + e)] : raw[NE + e];
    e32[e] = r;
    e32[NE + e] = c;
    if ((unsigned int)r < NN && (unsigned int)c < NN) atomicAdd(&deg[c], 1);
}

/* W -> bf16 [o][k]; block 256 converts bias/gamma/beta params */
__global__ void g_cvt_w(const void* W, const void* bias, const void* gamma,
                        const void* beta, const int* flags, unsigned short* Wb,
                        float* pf) {
    int ff = flags[0];
    int t = threadIdx.x;
    if (blockIdx.x == 256) {
        pf[t] = rdF(bias, t, ff);
        pf[DD + t] = rdF(gamma, t, ff);
        pf[2 * DD + t] = rdF(beta, t, ff);
        return;
    }
    int i = blockIdx.x * 256 + t;
    Wb[i] = f2b_rne(rdF(W, i, ff));
}

/* scan1 also emits dinv */
__global__ __launch_bounds__(256) void g_scan1(const int* deg, int* off, int* bsum,
                                               float* dinv) {
    __shared__ int sm[256];
    int tid = threadIdx.x;
    int i = blockIdx.x * 256 + tid;
    int v = (i < NN) ? deg[i] : 0;
    sm[tid] = v;
    __syncthreads();
    for (int s = 1; s < 256; s <<= 1) {
        int t = (tid >= s) ? sm[tid - s] : 0;
        __syncthreads();
        sm[tid] += t;
        __syncthreads();
    }
    if (i < NN) {
        off[i] = sm[tid] - v;
        dinv[i] = rsqrtf((float)(v + 1));
    }
    if (tid == 255) bsum[blockIdx.x] = sm[255];
}

__global__ __launch_bounds__(256) void g_scan2(const int* bsum, int* bbase) {
    __shared__ int sm[256];
    int tid = threadIdx.x;
    int v = (tid < 196) ? bsum[tid] : 0;
    sm[tid] = v;
    __syncthreads();
    for (int s = 1; s < 256; s <<= 1) {
        int t = (tid >= s) ? sm[tid - s] : 0;
        __syncthreads();
        sm[tid] += t;
        __syncthreads();
    }
    if (tid < 196) bbase[tid] = sm[tid] - v;
}

__global__ void g_scan3(int* off, const int* bbase, int* cursor) {
    int i = blockIdx.x * 256 + threadIdx.x;
    if (i < NN) {
        int o = off[i] + bbase[i >> 8];
        off[i] = o;
        cursor[i] = o;
    }
}

/* MFMA GEMM, B staged in LDS (R19): block = 64 rows x 64 cols, 4 waves.
   Wb col-tile (64 rows x 256 k bf16 = 32 KB) staged coalesced into LDS
   with 528B row pitch (264 shorts): fragment ds_read_b128 then spreads
   8 lanes per 4-bank group = LDS throughput floor (G4/m136).
   Fixes R18's TA scatter: B-loads were 128 instr x 16 scattered lines/wave.
   C/D: col = lane&15, row = (lane>>4)*4 + reg  (m89-verified mapping) */
#define WP 264 /* LDS row pitch in shorts (512B data + 16B pad) */
__global__ __launch_bounds__(256) void g_gemm_mfma(const void* x, const int* flags,
                                                   const unsigned short* Wb,
                                                   const float* dinv, _Float16* h) {
    __shared__ unsigned short wlds[64 * WP]; /* 33792 B */
    int t = threadIdx.x;
    int rt = blockIdx.x >> 2;   /* row-tile 0..781 */
    int ctile = blockIdx.x & 3; /* col-tile 0..3 */

    /* stage: 64 rows x 256 shorts = 2048 16B-chunks; 256 thr x 8 iters */
    const unsigned short* wsrc = Wb + ctile * 64 * DD;
#pragma unroll
    for (int i = 0; i < 8; i++) {
        int c = t + i * 256;
        int row = c >> 5;          /* 32 chunks per row */
        int off = (c & 31) * 8;    /* short offset in row */
        bf16x8 v = *(const bf16x8*)(wsrc + row * DD + off);
        *(bf16x8*)(&wlds[row * WP + off]) = v;
    }
    __syncthreads();

    int wave = t >> 6;
    int lane = t & 63;
    int rw = rt * 4 + wave;
    if (rw >= 3125) return; /* after barrier: safe */
    int r0 = rw * 16;
    int l15 = lane & 15;
    int kq = lane >> 4;

    bf16x8 a[8];
    int ff = flags[0];
    if (ff) {
        const unsigned short* p =
            (const unsigned short*)x + (unsigned long long)(r0 + l15) * DD + kq * 8;
#pragma unroll
        for (int k = 0; k < 8; k++)
            a[k] = *(const bf16x8*)(p + k * 32);
    } else {
        const float* p = (const float*)x + (unsigned long long)(r0 + l15) * DD + kq * 8;
#pragma unroll
        for (int k = 0; k < 8; k++) {
#pragma unroll
            for (int j = 0; j < 8; j++)
                a[k][j] = (short)f2b_rne(p[k * 32 + j]);
        }
    }

    float dv[4];
#pragma unroll
    for (int j = 0; j < 4; j++) dv[j] = dinv[r0 + kq * 4 + j];

    f32x4 acc[4];
#pragma unroll
    for (int ct = 0; ct < 4; ct++) acc[ct] = (f32x4){0.f, 0.f, 0.f, 0.f};

#pragma unroll
    for (int k = 0; k < 8; k++) {
        bf16x8 bfr[4];
#pragma unroll
        for (int ct = 0; ct < 4; ct++)
            bfr[ct] = *(const bf16x8*)(&wlds[(ct * 16 + l15) * WP + kq * 8 + k * 32]);
#pragma unroll
        for (int ct = 0; ct < 4; ct++)
            acc[ct] = __builtin_amdgcn_mfma_f32_16x16x32_bf16(a[k], bfr[ct], acc[ct],
                                                              0, 0, 0);
    }

#pragma unroll
    for (int ct = 0; ct < 4; ct++) {
        _Float16* op = h + (unsigned long long)(r0 + kq * 4) * DD + ctile * 64 +
                       ct * 16 + l15;
#pragma unroll
        for (int j = 0; j < 4; j++)
            op[(unsigned long long)j * DD] = (_Float16)(acc[ct][j] * dv[j]);
    }
}

__global__ void g_fill(const int* erow, const int* ecol, int* cursor, int* csrc) {
    int e = blockIdx.x * 256 + threadIdx.x;
    if (e < NE) {
        unsigned int c = (unsigned int)ecol[e];
        unsigned int r = (unsigned int)erow[e];
        if (c < NN && r < NN) {
            int slot = atomicAdd(&cursor[c], 1);
            if ((unsigned int)slot < NE) csrc[slot] = (int)r;
        }
    }
}

/* aggregate + bias -> fp16 agg. one node per wave, lane owns 4 features.
   agg[n] = dn*(h'[n] + sum h'[src]) + bias, h' pre-scaled by dinv in GEMM.
   8-deep unroll: 8 independent 512B row loads in flight per wave. */
__global__ __launch_bounds__(256) void g_agg(const _Float16* h, const float* dinv,
                                             const int* off, const int* deg,
                                             const int* csrc, const float* pf,
                                             _Float16* agg) {
    int lane = threadIdx.x & 63;
    int n = blockIdx.x * 4 + (threadIdx.x >> 6);
    int f0 = lane * 4;
    int s = __builtin_amdgcn_readfirstlane(off[n]);
    int cnt = __builtin_amdgcn_readfirstlane(deg[n]);
    float dn = dinv[n];
    f16x4 hv = *(const f16x4*)(h + (unsigned long long)n * DD + f0);
    float a0 = (float)hv[0];
    float a1 = (float)hv[1];
    float a2 = (float)hv[2];
    float a3 = (float)hv[3];
    const int* ip = csrc + s;
    int k = 0;
    for (; k + 8 <= cnt; k += 8) {
        int i0 = ip[k + 0], i1 = ip[k + 1], i2 = ip[k + 2], i3 = ip[k + 3];
        int i4 = ip[k + 4], i5 = ip[k + 5], i6 = ip[k + 6], i7 = ip[k + 7];
        f16x4 v0 = *(const f16x4*)(h + (unsigned long long)i0 * DD + f0);
        f16x4 v1 = *(const f16x4*)(h + (unsigned long long)i1 * DD + f0);
        f16x4 v2 = *(const f16x4*)(h + (unsigned long long)i2 * DD + f0);
        f16x4 v3 = *(const f16x4*)(h + (unsigned long long)i3 * DD + f0);
        f16x4 v4 = *(const f16x4*)(h + (unsigned long long)i4 * DD + f0);
        f16x4 v5 = *(const f16x4*)(h + (unsigned long long)i5 * DD + f0);
        f16x4 v6 = *(const f16x4*)(h + (unsigned long long)i6 * DD + f0);
        f16x4 v7 = *(const f16x4*)(h + (unsigned long long)i7 * DD + f0);
        a0 += (((float)v0[0] + (float)v1[0]) + ((float)v2[0] + (float)v3[0])) +
              (((float)v4[0] + (float)v5[0]) + ((float)v6[0] + (float)v7[0]));
        a1 += (((float)v0[1] + (float)v1[1]) + ((float)v2[1] + (float)v3[1])) +
              (((float)v4[1] + (float)v5[1]) + ((float)v6[1] + (float)v7[1]));
        a2 += (((float)v0[2] + (float)v1[2]) + ((float)v2[2] + (float)v3[2])) +
              (((float)v4[2] + (float)v5[2]) + ((float)v6[2] + (float)v7[2]));
        a3 += (((float)v0[3] + (float)v1[3]) + ((float)v2[3] + (float)v3[3])) +
              (((float)v4[3] + (float)v5[3]) + ((float)v6[3] + (float)v7[3]));
    }
    for (; k + 4 <= cnt; k += 4) {
        int i0 = ip[k + 0], i1 = ip[k + 1], i2 = ip[k + 2], i3 = ip[k + 3];
        f16x4 v0 = *(const f16x4*)(h + (unsigned long long)i0 * DD + f0);
        f16x4 v1 = *(const f16x4*)(h + (unsigned long long)i1 * DD + f0);
        f16x4 v2 = *(const f16x4*)(h + (unsigned long long)i2 * DD + f0);
        f16x4 v3 = *(const f16x4*)(h + (unsigned long long)i3 * DD + f0);
        a0 += ((float)v0[0] + (float)v1[0]) + ((float)v2[0] + (float)v3[0]);
        a1 += ((float)v0[1] + (float)v1[1]) + ((float)v2[1] + (float)v3[1]);
        a2 += ((float)v0[2] + (float)v1[2]) + ((float)v2[2] + (float)v3[2]);
        a3 += ((float)v0[3] + (float)v1[3]) + ((float)v2[3] + (float)v3[3]);
    }
    for (; k < cnt; k++) {
        int i0 = ip[k];
        f16x4 v0 = *(const f16x4*)(h + (unsigned long long)i0 * DD + f0);
        a0 += (float)v0[0];
        a1 += (float)v0[1];
        a2 += (float)v0[2];
        a3 += (float)v0[3];
    }
    f16x4 o;
    o[0] = (_Float16)(dn * a0 + pf[f0 + 0]);
    o[1] = (_Float16)(dn * a1 + pf[f0 + 1]);
    o[2] = (_Float16)(dn * a2 + pf[f0 + 2]);
    o[3] = (_Float16)(dn * a3 + pf[f0 + 3]);
    *(f16x4*)(agg + (unsigned long long)n * DD + f0) = o;
}

/* stats over fp16 agg */
__global__ __launch_bounds__(256) void g_stats(const _Float16* agg, float* sums) {
    int t = threadIdx.x;
    float s = 0.f;
    float s2 = 0.f;
    for (int n = blockIdx.x; n < NN; n += 256) {
        float v = (float)agg[(unsigned long long)n * DD + t];
        s += v;
        s2 += v * v;
    }
    atomicAdd(&sums[t], s);
    atomicAdd(&sums[DD + t], s2);
}

__global__ void g_fin(const float* sums, const float* pf, float* ss) {
    int t = threadIdx.x;
    float mean = sums[t] * (1.0f / NN);
    float var = sums[DD + t] * (1.0f / NN) - mean * mean;
    var = fmaxf(var, 0.f);
    float sc = pf[DD + t] * rsqrtf(var + 1e-5f);
    ss[t] = sc;
    ss[DD + t] = pf[2 * DD + t] - mean * sc;
}

/* BN + ReLU: fp16 agg -> fp32 out. 8 elems/thread, grid 6250. */
__global__ void DenseGCNLayer_2937757631000_kernel(const _Float16* agg, const float* ss,
                                                   float* out) {
    int t = threadIdx.x;
    unsigned long long base =
        (unsigned long long)blockIdx.x * 2048 + (unsigned int)t * 8;
    int f = (int)(base & 255);
    f16x8 v = *(const f16x8*)(agg + base);
    f32x4 o0, o1;
#pragma unroll
    for (int j = 0; j < 4; j++)
        o0[j] = fmaxf(ss[f + j] * (float)v[j] + ss[DD + f + j], 0.f);
#pragma unroll
    for (int j = 0; j < 4; j++)
        o1[j] = fmaxf(ss[f + 4 + j] * (float)v[4 + j] + ss[DD + f + 4 + j], 0.f);
    *(f32x4*)(out + base) = o0;
    *(f32x4*)(out + base + 4) = o1;
}

extern "C" void kernel_launch(void* const* d_in, const int* in_sizes, int n_in,
                              void* d_out, int out_size, void* d_ws, size_t ws_size,
                              hipStream_t stream) {
    const void* x = d_in[0];
    const int* ei = (const int*)d_in[1];
    const void* W = d_in[2];
    const void* bias = d_in[3];
    const void* gamma = d_in[4];
    const void* beta = d_in[5];
    char* ws = (char*)d_ws;
    float* out = (float*)d_out;

    _Float16* h = (_Float16*)(ws + 0UL);          /* 25.6 MB fp16 */
    _Float16* agg = (_Float16*)(ws + 51200000UL); /* 25.6 MB fp16 */
    int* e32 = (int*)(ws + 102400000UL);          /* 6.4 MB */
    int* csrc = (int*)(ws + 108800000UL);         /* 3.2 MB */
    unsigned short* Wb = (unsigned short*)(ws + 112000000UL); /* 128 KB bf16 */
    int* deg = (int*)(ws + 112262144UL);
    float* dinv = (float*)(ws + 112462336UL);
    int* off = (int*)(ws + 112662528UL);
    int* cursor = (int*)(ws + 112862720UL);
    int* bsum = (int*)(ws + 113062912UL);
    int* bbase = (int*)(ws + 113063936UL);
    float* pf = (float*)(ws + 113064960UL);
    float* sums = (float*)(ws + 113068032UL);
    float* ss = (float*)(ws + 113070080UL);
    int* flags = (int*)(ws + 113072128UL);
    const int* erow = e32;
    const int* ecol = e32 + NE;

    if (ws_size < WS_NEED) {
        fprintf(stderr, "R19_WS_SMALL %zu\n", ws_size);
        fflush(stderr);
        return;
    }

    g_zero<<<197, 256, 0, stream>>>(deg, sums, (const unsigned short*)x, ei, flags);
    g_cvt_ed<<<3125, 256, 0, stream>>>(ei, flags, e32, deg);
    g_cvt_w<<<257, 256, 0, stream>>>(W, bias, gamma, beta, flags, Wb, pf);
    g_scan1<<<196, 256, 0, stream>>>(deg, off, bsum, dinv);
    g_scan2<<<1, 256, 0, stream>>>(bsum, bbase);
    g_scan3<<<196, 256, 0, stream>>>(off, bbase, cursor);
    g_gemm_mfma<<<3128, 256, 0, stream>>>(x, flags, Wb, dinv, h);
    g_fill<<<3125, 256, 0, stream>>>(erow, ecol, cursor, csrc);
    g_agg<<<12500, 256, 0, stream>>>(h, dinv, off, deg, csrc, pf, agg);
    g_stats<<<256, 256, 0, stream>>>(agg, sums);
    g_fin<<<1, 256, 0, stream>>>(sums, pf, ss);
    DenseGCNLayer_2937757631000_kernel<<<6250, 256, 0, stream>>>(agg, ss, out);
}